// Round 12
// baseline (791.562 us; speedup 1.0000x reference)
//
#include <hip/hip_runtime.h>
#include <hip/hip_bf16.h>
#include <math.h>

// Problem constants (from reference)
#define N_NODES 10000
#define N_EDGES 80000
#define N_GRAPHS 64
#define NH 4
#define HD 512
#define HDTOT 2048   // NH*HD
#define EMB 768
#define HFEAT 512

typedef _Float16 half8 __attribute__((ext_vector_type(8)));
typedef _Float16 half4 __attribute__((ext_vector_type(4)));
typedef float f32x4 __attribute__((ext_vector_type(4)));

// Async global->LDS, 16B per lane. LDS dest = wave-uniform base + lane*16;
// the GLOBAL SOURCE ADDRESS IS PER-LANE. Lanes fetch their row's K-granules
// in XOR-permuted order (g8 ^ (r&7)), so the DMA lands a swizzled LDS image
// from a PLAIN row-major global plane. With BK=64 (row stride 128 B = all 32
// banks), fragment ds_read_b128s at granule (kk*4+fq)^(m&7) hit 8 bank
// groups x 2 lanes = 2-way aliasing (free). Zero VALU repack.
__device__ __forceinline__ void gload_lds16(const void* g, void* l) {
  __builtin_amdgcn_global_load_lds(
      (const __attribute__((address_space(1))) unsigned int*)g,
      (__attribute__((address_space(3))) unsigned int*)l, 16, 0, 0);
}

// ---------------------------------------------------------------------------
// Plain-fp16 MFMA GEMM: C = act(A @ B + bias), C stored as fp16 plane.
// A: MxK fp16 row-major. BT: NxK fp16 row-major (plain transpose).
// BOTH staged via source-swizzled global_load_lds. BK=64.
// Epilogue: per-wave LDS bounce -> 16B coalesced C stores. Optionally fuses
// the GAT attention-logit partials: el[n,h] += sum_col C[n,col]*al[col]
// (al/ar indexed by the GLOBAL column; h = bn>>9). Reduction: in-register
// over ni, shuffle over the 16 fr lanes, LDS accumulate, one global
// atomicAdd per row per block.
// Tile BM x 128, 256 threads. BM=128: waves 2x2; BM=64: 1x4. K%64==0.
// ---------------------------------------------------------------------------
template <int BM>
__global__ __launch_bounds__(256) void gemm_f16_kernel(
    const _Float16* __restrict__ A, const _Float16* __restrict__ BT,
    const float* __restrict__ bias, _Float16* __restrict__ C,
    int M, int N, int K, int act,
    const float* __restrict__ al, const float* __restrict__ ar,
    float* __restrict__ el_g, float* __restrict__ er_g) {
  constexpr int WR = (BM == 128) ? 2 : 1;  // wave grid rows
  constexpr int WC = 4 / WR;               // wave grid cols
  constexpr int MI = (BM / WR) / 16;       // m-frags per wave (4)
  constexpr int NI = (128 / WC) / 16;      // n-frags per wave (4 or 2)
  constexpr int NW = NI * 16;              // wave n-width (64 or 32)
  constexpr int CS = NW + 4;               // epilogue scratch row stride
  constexpr int GPR = NW / 8;              // 16B granules per scratch row

  __shared__ _Float16 smem[(BM + 128) * 64];
  __shared__ float elp[BM], erp[BM];
  _Float16* As = smem;             // BM x 64 (swizzled image)
  _Float16* Bs = smem + BM * 64;   // 128 x 64 (swizzled image)

  const int bn = blockIdx.x * 128, bm = blockIdx.y * BM;
  const int t = threadIdx.x;
  const int lane = t & 63, wave = t >> 6;
  const int wr = wave / WC, wc = wave % WC;
  const int m0 = wr * (BM / WR), n0 = wc * NW;
  const int fr = lane & 15, fq = lane >> 4;

  f32x4 acc[MI][NI];
#pragma unroll
  for (int i = 0; i < MI; ++i)
#pragma unroll
    for (int j = 0; j < NI; ++j) acc[i][j] = (f32x4){0.f, 0.f, 0.f, 0.f};

  for (int k0 = 0; k0 < K; k0 += 64) {
    __syncthreads();  // protect LDS from previous iteration's readers
    // ---- stage A via source-swizzled global_load_lds: BM x 64 ----
#pragma unroll
    for (int it = 0; it < BM / 32; ++it) {
      int gid = it * 256 + t;
      int r = gid >> 3;
      int q = (gid & 7) ^ (r & 7);  // fetch permuted granule
      int grow = bm + r;
      if (grow >= M) grow = M - 1;  // clamp; garbage masked in epilogue
      gload_lds16(A + (size_t)grow * K + k0 + q * 8,
                  &As[(it * 256 + wave * 64) * 8]);
    }
    // ---- stage B via source-swizzled global_load_lds: 128 x 64 ----
#pragma unroll
    for (int it = 0; it < 4; ++it) {
      int gid = it * 256 + t;
      int r = gid >> 3;
      int q = (gid & 7) ^ (r & 7);
      gload_lds16(BT + (size_t)(bn + r) * K + k0 + q * 8,
                  &Bs[(it * 256 + wave * 64) * 8]);
    }
    __syncthreads();

#pragma unroll
    for (int kk = 0; kk < 2; ++kk) {
      half8 af[MI], bf[NI];
#pragma unroll
      for (int mi = 0; mi < MI; ++mi) {
        int m = m0 + mi * 16 + fr;
        af[mi] = *(const half8*)&As[m * 64 + (((kk * 4 + fq) ^ (m & 7))) * 8];
      }
#pragma unroll
      for (int ni = 0; ni < NI; ++ni) {
        int n = n0 + ni * 16 + fr;
        bf[ni] = *(const half8*)&Bs[n * 64 + (((kk * 4 + fq) ^ (n & 7))) * 8];
      }
#pragma unroll
      for (int mi = 0; mi < MI; ++mi)
#pragma unroll
        for (int ni = 0; ni < NI; ++ni)
          acc[mi][ni] = __builtin_amdgcn_mfma_f32_16x16x32_f16(
              af[mi], bf[ni], acc[mi][ni], 0, 0, 0);
    }
  }
  // ---- epilogue ----
  __syncthreads();  // all K-loop LDS reads done; staging smem reusable
  if (el_g && t < BM) { elp[t] = 0.f; erp[t] = 0.f; }
  if (el_g) __syncthreads();

  _Float16* cs = smem + wave * 16 * CS;  // wave-private scratch (16 x CS)
  float av[NI], rv[NI];
  if (el_g) {
#pragma unroll
    for (int ni = 0; ni < NI; ++ni) {
      av[ni] = al[bn + n0 + ni * 16 + fr];
      rv[ni] = ar[bn + n0 + ni * 16 + fr];
    }
  }
#pragma unroll
  for (int mi = 0; mi < MI; ++mi) {
#pragma unroll
    for (int ni = 0; ni < NI; ++ni) {
      float bb = bias ? bias[bn + n0 + ni * 16 + fr] : 0.f;
#pragma unroll
      for (int j = 0; j < 4; ++j) {
        float v = acc[mi][ni][j] + bb;
        if (act == 1) v = v > 0.f ? v : expm1f(v);
        cs[(fq * 4 + j) * CS + ni * 16 + fr] = (_Float16)v;
      }
    }
    if (el_g) {
      // partial attention logits for this wave's rows
#pragma unroll
      for (int j = 0; j < 4; ++j) {
        float pe = 0.f, pr = 0.f;
#pragma unroll
        for (int ni = 0; ni < NI; ++ni) {
          pe += acc[mi][ni][j] * av[ni];
          pr += acc[mi][ni][j] * rv[ni];
        }
#pragma unroll
        for (int off = 1; off < 16; off <<= 1) {
          pe += __shfl_xor(pe, off);
          pr += __shfl_xor(pr, off);
        }
        if (fr == 0) {
          int lrow = m0 + mi * 16 + fq * 4 + j;
          atomicAdd(&elp[lrow], pe);
          atomicAdd(&erp[lrow], pr);
        }
      }
    }
    // wave-local read-back (compiler orders LDS ops via lgkmcnt)
#pragma unroll
    for (int i = 0; i < NW / 32; ++i) {
      int piece = i * 64 + lane;
      int r = piece / GPR, g = piece % GPR;
      int grow = bm + m0 + mi * 16 + r;
      if (grow < M) {
        half8 v = *(const half8*)&cs[r * CS + g * 8];
        *(half8*)&C[(size_t)grow * N + bn + n0 + g * 8] = v;
      }
    }
  }
  if (el_g) {
    __syncthreads();  // all LDS atomics done
    int h = bn >> 9;  // head of this 128-col strip (HD=512)
    if (t < BM && bm + t < M) {
      atomicAdd(&el_g[(bm + t) * NH + h], elp[t]);
      atomicAdd(&er_g[(bm + t) * NH + h], erp[t]);
    }
  }
}

// ---------------------------------------------------------------------------
// Transpose + convert weights: W (KxN fp32) -> WT (NxK fp16), PLAIN layout.
// blockIdx.z batches matrices (stride K*N).
// ---------------------------------------------------------------------------
__global__ __launch_bounds__(256) void convert_wt_kernel(
    const float* __restrict__ W, _Float16* __restrict__ WT, int K, int N) {
  __shared__ float tile[32][33];
  W += (size_t)blockIdx.z * K * N;
  WT += (size_t)blockIdx.z * K * N;
  int k0 = blockIdx.x * 32, n0 = blockIdx.y * 32;
  int t = threadIdx.x;
  int r = t >> 3, c4 = (t & 7) * 4;
  float4 v = *(const float4*)(W + (size_t)(k0 + r) * N + n0 + c4);
  tile[r][c4 + 0] = v.x;
  tile[r][c4 + 1] = v.y;
  tile[r][c4 + 2] = v.z;
  tile[r][c4 + 3] = v.w;
  __syncthreads();
  float x0 = tile[c4 + 0][r], x1 = tile[c4 + 1][r];
  float x2 = tile[c4 + 2][r], x3 = tile[c4 + 3][r];
  size_t o = (size_t)(n0 + r) * K + k0 + c4;
  *(half4*)&WT[o] = (half4){(_Float16)x0, (_Float16)x1, (_Float16)x2, (_Float16)x3};
}

// fp32 -> fp16 plane (for the external node_feat input)
__global__ void convert_f32_f16_kernel(const float* __restrict__ x,
                                       _Float16* __restrict__ y, int n4) {
  int gid = blockIdx.x * blockDim.x + threadIdx.x;
  if (gid >= n4) return;
  float4 v = *(const float4*)(x + gid * 4);
  *(half4*)(y + gid * 4) =
      (half4){(_Float16)v.x, (_Float16)v.y, (_Float16)v.z, (_Float16)v.w};
}

// ---------------------------------------------------------------------------
// CSR build (by dst): histogram -> single-block scan -> scatter.
// Scatter packs src into CSR order (csr_src).
// ---------------------------------------------------------------------------
__global__ void hist_kernel(const int* __restrict__ dst, int* __restrict__ cnt, int E) {
  int gid = blockIdx.x * blockDim.x + threadIdx.x;
  if (gid < E) atomicAdd(&cnt[dst[gid]], 1);
}

__global__ void scan_kernel(const int* __restrict__ cnt, int* __restrict__ row_ptr,
                            int* __restrict__ cursor, int n) {
  __shared__ int part[256];
  int t = threadIdx.x;
  int chunk = (n + 255) / 256;
  int s0 = t * chunk;
  int s1 = min(s0 + chunk, n);
  int sum = 0;
  for (int i = s0; i < s1; ++i) sum += cnt[i];
  part[t] = sum;
  __syncthreads();
  if (t == 0) {
    int acc = 0;
    for (int i = 0; i < 256; ++i) { int v = part[i]; part[i] = acc; acc += v; }
    row_ptr[n] = acc;
  }
  __syncthreads();
  int run = part[t];
  for (int i = s0; i < s1; ++i) {
    row_ptr[i] = run;
    cursor[i] = run;
    run += cnt[i];
  }
}

__global__ void scatter_kernel(const int* __restrict__ src, const int* __restrict__ dst,
                               int* __restrict__ cursor, int* __restrict__ csr_src,
                               int E) {
  int gid = blockIdx.x * blockDim.x + threadIdx.x;
  if (gid < E) {
    int d = dst[gid];
    int pos = atomicAdd(&cursor[d], 1);
    csr_src[pos] = src[gid];
  }
}

// ---------------------------------------------------------------------------
// Fused per-(node,head) edge softmax: leaky-relu logits over the CSR range
// -> max -> exp -> sum -> write NORMALIZED weights (a = ex * (1/sum)).
// Fast path (degree <= 64): logits stay in registers, single gather pass.
// ---------------------------------------------------------------------------
__global__ __launch_bounds__(256) void edge_softmax_kernel(
    const float* __restrict__ el, const float* __restrict__ er,
    const int* __restrict__ csr_src, const int* __restrict__ row_ptr,
    float* __restrict__ e_buf) {
  int n = blockIdx.x;
  int t = threadIdx.x;
  int h = t >> 6, lane = t & 63;
  int s = row_ptr[n], epos = row_ptr[n + 1];
  int deg = epos - s;
  if (deg == 0) return;
  float ern = er[n * NH + h];
  if (deg <= 64) {
    int p = s + lane;
    bool on = lane < deg;
    float logit = 0.f;
    float m = -INFINITY;
    if (on) {
      float v = el[csr_src[p] * NH + h] + ern;
      logit = v >= 0.f ? v : 0.2f * v;
      m = logit;
    }
#pragma unroll
    for (int off = 32; off; off >>= 1) m = fmaxf(m, __shfl_xor(m, off));
    float ex = on ? expf(logit - m) : 0.f;
    float sum = ex;
#pragma unroll
    for (int off = 32; off; off >>= 1) sum += __shfl_xor(sum, off);
    float inv = 1.f / sum;
    if (on) e_buf[p * NH + h] = ex * inv;
    return;
  }
  float m = -INFINITY;
  for (int p = s + lane; p < epos; p += 64) {
    float v = el[csr_src[p] * NH + h] + ern;
    v = v >= 0.f ? v : 0.2f * v;
    e_buf[p * NH + h] = v;
    m = fmaxf(m, v);
  }
  for (int off = 32; off; off >>= 1) m = fmaxf(m, __shfl_xor(m, off));
  float sum = 0.f;
  for (int p = s + lane; p < epos; p += 64) {
    float ex = expf(e_buf[p * NH + h] - m);
    e_buf[p * NH + h] = ex;
    sum += ex;
  }
  for (int off = 32; off; off >>= 1) sum += __shfl_xor(sum, off);
  float inv = 1.f / sum;
  for (int p = s + lane; p < epos; p += 64) e_buf[p * NH + h] *= inv;
}

// out[n,:] = sum over CSR range feat[csr_src[p],:]*a[p] + bias.
// 4-deep edge unroll for memory-level parallelism (L3-latency hiding).
__global__ __launch_bounds__(256) void aggregate_kernel(
    const _Float16* __restrict__ feat, const float* __restrict__ e_buf,
    const int* __restrict__ row_ptr, const int* __restrict__ csr_src,
    const float* __restrict__ bias, _Float16* __restrict__ out) {
  int n = blockIdx.x;
  int t = threadIdx.x;
  int base = t * 8;
  int h = t >> 6;
  float acc[8] = {0.f, 0.f, 0.f, 0.f, 0.f, 0.f, 0.f, 0.f};
  int s = row_ptr[n], epos = row_ptr[n + 1];
  int p = s;
  for (; p + 4 <= epos; p += 4) {
    int sn0 = csr_src[p + 0], sn1 = csr_src[p + 1];
    int sn2 = csr_src[p + 2], sn3 = csr_src[p + 3];
    float a0 = e_buf[(p + 0) * NH + h];
    float a1 = e_buf[(p + 1) * NH + h];
    float a2 = e_buf[(p + 2) * NH + h];
    float a3 = e_buf[(p + 3) * NH + h];
    half8 f0 = *(const half8*)(feat + (size_t)sn0 * HDTOT + base);
    half8 f1 = *(const half8*)(feat + (size_t)sn1 * HDTOT + base);
    half8 f2 = *(const half8*)(feat + (size_t)sn2 * HDTOT + base);
    half8 f3 = *(const half8*)(feat + (size_t)sn3 * HDTOT + base);
#pragma unroll
    for (int i = 0; i < 8; ++i)
      acc[i] += a0 * (float)f0[i] + a1 * (float)f1[i] +
                a2 * (float)f2[i] + a3 * (float)f3[i];
  }
  for (; p < epos; ++p) {
    int sn = csr_src[p];
    float a = e_buf[p * NH + h];
    half8 f = *(const half8*)(feat + (size_t)sn * HDTOT + base);
#pragma unroll
    for (int i = 0; i < 8; ++i) acc[i] += a * (float)f[i];
  }
  float4 b0 = *(const float4*)(bias + base);
  float4 b1 = *(const float4*)(bias + base + 4);
  half8 o;
  o[0] = (_Float16)(acc[0] + b0.x); o[1] = (_Float16)(acc[1] + b0.y);
  o[2] = (_Float16)(acc[2] + b0.z); o[3] = (_Float16)(acc[3] + b0.w);
  o[4] = (_Float16)(acc[4] + b1.x); o[5] = (_Float16)(acc[5] + b1.y);
  o[6] = (_Float16)(acc[6] + b1.z); o[7] = (_Float16)(acc[7] + b1.w);
  *(half8*)(out + (size_t)n * HDTOT + base) = o;
}

// ---------------------------------------------------------------------------
// Pooling (graph_id sorted -> segmented reduction) + head
// ---------------------------------------------------------------------------
__global__ __launch_bounds__(512) void pool_kernel(
    const _Float16* __restrict__ h, const int* __restrict__ graph_id,
    float* __restrict__ hg, float* __restrict__ counts) {
  int g = blockIdx.x;
  __shared__ int s_lo, s_hi;
  if (threadIdx.x == 0) {
    int lo = 0, hi = N_NODES;
    while (lo < hi) { int m = (lo + hi) >> 1; if (graph_id[m] < g) lo = m + 1; else hi = m; }
    s_lo = lo;
    int lo2 = lo, hi2 = N_NODES;
    while (lo2 < hi2) { int m = (lo2 + hi2) >> 1; if (graph_id[m] < g + 1) lo2 = m + 1; else hi2 = m; }
    s_hi = lo2;
  }
  __syncthreads();
  int lo = s_lo, hi = s_hi;
  int col = threadIdx.x;
  float acc = 0.f;
  for (int n = lo; n < hi; ++n) acc += (float)h[(size_t)n * HFEAT + col];
  hg[g * HFEAT + col] = acc;
  if (col == 0) counts[g] = (float)(hi - lo);
}

__global__ __launch_bounds__(256) void final_kernel(
    const float* __restrict__ hg, const float* __restrict__ counts,
    const float* __restrict__ gamma, const float* __restrict__ beta,
    const float* __restrict__ Whfc, const float* __restrict__ bhfc,
    const float* __restrict__ Wf, const float* __restrict__ bf,
    float* __restrict__ out) {
  __shared__ float sh[HFEAT];
  __shared__ float st[HFEAT];
  __shared__ float r0[4], r1[4];
  int g = blockIdx.x, t = threadIdx.x;
  float invc = 1.f / fmaxf(counts[g], 1.f);
  float bnscale = rsqrtf(1.f + 1e-5f);
  for (int j = t; j < HFEAT; j += 256) {
    float v = hg[g * HFEAT + j] * invc;
    sh[j] = v * bnscale * gamma[j] + beta[j];
  }
  __syncthreads();
  for (int j = t; j < HFEAT; j += 256) {
    float acc = bhfc[j];
    for (int k = 0; k < HFEAT; ++k) acc += sh[k] * Whfc[k * HFEAT + j];
    st[j] = acc > 0.f ? acc : expm1f(acc);
  }
  __syncthreads();
  float p0 = 0.f, p1 = 0.f;
  for (int j = t; j < HFEAT; j += 256) {
    p0 += st[j] * Wf[j * 2 + 0];
    p1 += st[j] * Wf[j * 2 + 1];
  }
  for (int off = 32; off; off >>= 1) {
    p0 += __shfl_down(p0, off);
    p1 += __shfl_down(p1, off);
  }
  int w = t >> 6;
  if ((t & 63) == 0) { r0[w] = p0; r1[w] = p1; }
  __syncthreads();
  if (t == 0) {
    out[g * 2 + 0] = r0[0] + r0[1] + r0[2] + r0[3] + bf[0];
    out[g * 2 + 1] = r1[0] + r1[1] + r1[2] + r1[3] + bf[1];
  }
}

// ---------------------------------------------------------------------------
// Host-side launch
// ---------------------------------------------------------------------------
static void gemm_raw(const _Float16* A, const _Float16* wt, const float* bias,
                     _Float16* C, int M, int N, int K, int act,
                     bool small_m_tile, hipStream_t stream,
                     const float* al = nullptr, const float* ar = nullptr,
                     float* el = nullptr, float* er = nullptr) {
  if (small_m_tile) {
    dim3 grid(N / 128, (M + 63) / 64);
    hipLaunchKernelGGL(gemm_f16_kernel<64>, grid, dim3(256), 0, stream,
                       A, wt, bias, C, M, N, K, act, al, ar, el, er);
  } else {
    dim3 grid(N / 128, (M + 127) / 128);
    hipLaunchKernelGGL(gemm_f16_kernel<128>, grid, dim3(256), 0, stream,
                       A, wt, bias, C, M, N, K, act, al, ar, el, er);
  }
}

static void gemm(const _Float16* A, const float* W, _Float16* wt,
                 const float* bias, _Float16* C, int M, int N, int K, int act,
                 bool small_m_tile, hipStream_t stream,
                 const float* al = nullptr, const float* ar = nullptr,
                 float* el = nullptr, float* er = nullptr) {
  hipLaunchKernelGGL(convert_wt_kernel, dim3(K / 32, N / 32, 1), dim3(256),
                     0, stream, W, wt, K, N);
  gemm_raw(A, wt, bias, C, M, N, K, act, small_m_tile, stream, al, ar, el, er);
}

static void gat_layer(const _Float16* h_in, int K_in, const float* W, _Float16* wt,
                      const float* al, const float* ar, const float* b,
                      const int* row_ptr, const int* csr_src,
                      _Float16* featbuf, float* el, float* er,
                      float* e_buf, _Float16* out, hipStream_t stream) {
  // zero logit accumulators (el, er contiguous)
  hipMemsetAsync(el, 0, 2 * N_NODES * NH * sizeof(float), stream);
  // feat GEMM with fused el/er partial reduction
  gemm(h_in, W, wt, nullptr, featbuf, N_NODES, HDTOT, K_in, 0, false, stream,
       al, ar, el, er);
  hipLaunchKernelGGL(edge_softmax_kernel, dim3(N_NODES), dim3(256), 0, stream,
                     el, er, csr_src, row_ptr, e_buf);
  hipLaunchKernelGGL(aggregate_kernel, dim3(N_NODES), dim3(256), 0, stream,
                     featbuf, e_buf, row_ptr, csr_src, b, out);
}

extern "C" void kernel_launch(void* const* d_in, const int* in_sizes, int n_in,
                              void* d_out, int out_size, void* d_ws, size_t ws_size,
                              hipStream_t stream) {
  const float* node_feat = (const float*)d_in[0];
  const float* W1 = (const float*)d_in[2];
  const float* al1 = (const float*)d_in[3];
  const float* ar1 = (const float*)d_in[4];
  const float* b1 = (const float*)d_in[5];
  const float* W2 = (const float*)d_in[6];
  const float* al2 = (const float*)d_in[7];
  const float* ar2 = (const float*)d_in[8];
  const float* b2 = (const float*)d_in[9];
  const float* Wfc = (const float*)d_in[10];
  const float* bfc = (const float*)d_in[11];
  const float* Wh = (const float*)d_in[14];
  const float* bh = (const float*)d_in[15];
  const float* gamma = (const float*)d_in[16];
  const float* beta = (const float*)d_in[17];
  const float* Whfc = (const float*)d_in[18];
  const float* bhfc = (const float*)d_in[19];
  const float* Wf = (const float*)d_in[20];
  const float* bf = (const float*)d_in[21];
  const int* src = (const int*)d_in[22];
  const int* dst = (const int*)d_in[23];
  const int* graph_id = (const int*)d_in[24];
  float* out = (float*)d_out;

  // Workspace carve-up
  _Float16* P0 = (_Float16*)d_ws;                 // 10000*2048 fp16
  _Float16* P1 = P0 + (size_t)N_NODES * HDTOT;    // 10000*2048 fp16
  _Float16* Pin = P1 + (size_t)N_NODES * HDTOT;   // 10000*768 fp16
  _Float16* wt = Pin + (size_t)N_NODES * EMB;     // 2048*2048 fp16 (shared)
  _Float16* whh = wt + (size_t)2048 * 2048;       // 8*512*512 fp16 (hidden)
  float* el = (float*)(whh + (size_t)8 * HFEAT * HFEAT);
  float* er = el + N_NODES * NH;          // contiguous after el
  float* e_buf = er + N_NODES * NH;       // N_EDGES*NH (CSR order, normalized)
  float* hg = e_buf + (size_t)N_EDGES * NH;
  float* counts = hg + N_GRAPHS * HFEAT;
  int* cnt = (int*)(counts + N_GRAPHS);
  int* row_ptr = cnt + N_NODES;           // N_NODES+1
  int* cursor = row_ptr + N_NODES + 1;
  int* csr_src = cursor + N_NODES;        // N_EDGES

  // --- CSR build (by dst), once per launch ---
  hipMemsetAsync(cnt, 0, N_NODES * sizeof(int), stream);
  hipLaunchKernelGGL(hist_kernel, dim3((N_EDGES + 255) / 256), dim3(256), 0, stream,
                     dst, cnt, N_EDGES);
  hipLaunchKernelGGL(scan_kernel, dim3(1), dim3(256), 0, stream, cnt, row_ptr, cursor, N_NODES);
  hipLaunchKernelGGL(scatter_kernel, dim3((N_EDGES + 255) / 256), dim3(256), 0, stream,
                     src, dst, cursor, csr_src, N_EDGES);

  // --- node_feat -> fp16 plane; hidden weights -> transposed fp16 (batched) ---
  int n4 = N_NODES * EMB / 4;
  hipLaunchKernelGGL(convert_f32_f16_kernel, dim3((n4 + 255) / 256), dim3(256), 0, stream,
                     node_feat, Pin, n4);
  hipLaunchKernelGGL(convert_wt_kernel, dim3(HFEAT / 32, HFEAT / 32, 8),
                     dim3(256), 0, stream, Wh, whh, HFEAT, HFEAT);

  // --- GAT layer 1: Pin(768) -> feat P0 -> h1 P1 (2048) ---
  gat_layer(Pin, EMB, W1, wt, al1, ar1, b1, row_ptr, csr_src,
            P0, el, er, e_buf, P1, stream);
  // --- GAT layer 2: P1(2048) -> feat P0 -> h2 P1 (2048) ---
  gat_layer(P1, HDTOT, W2, wt, al2, ar2, b2, row_ptr, csr_src,
            P0, el, er, e_buf, P1, stream);

  // --- h = elu(P1 @ Wfc + bfc) -> P0 (N x 512) ---
  gemm(P1, Wfc, wt, bfc, P0, N_NODES, HFEAT, HDTOT, 1, true, stream);

  // --- 8 hidden layers: chained gemm<64>, weights pre-converted ---
  _Float16* cur = P0;
  _Float16* nxt = P1;
  for (int i = 0; i < 8; ++i) {
    gemm_raw(cur, whh + (size_t)i * HFEAT * HFEAT, bh + (size_t)i * HFEAT, nxt,
             N_NODES, HFEAT, HFEAT, 1, true, stream);
    _Float16* tmp = cur; cur = nxt; nxt = tmp;
  }
  // after 8 swaps, cur == P0 holds the final h

  // --- mean pool per graph ---
  hipLaunchKernelGGL(pool_kernel, dim3(N_GRAPHS), dim3(512), 0, stream,
                     cur, graph_id, hg, counts);

  // --- BN + fc + classifier ---
  hipLaunchKernelGGL(final_kernel, dim3(N_GRAPHS), dim3(256), 0, stream,
                     hg, counts, gamma, beta, Whfc, bhfc, Wf, bf, out);
}

// Round 13
// 764.832 us; speedup vs baseline: 1.0349x; 1.0349x over previous
//
#include <hip/hip_runtime.h>
#include <hip/hip_bf16.h>
#include <math.h>

// Problem constants (from reference)
#define N_NODES 10000
#define N_EDGES 80000
#define N_GRAPHS 64
#define NH 4
#define HD 512
#define HDTOT 2048   // NH*HD
#define EMB 768
#define HFEAT 512

typedef _Float16 half8 __attribute__((ext_vector_type(8)));
typedef _Float16 half4 __attribute__((ext_vector_type(4)));
typedef float f32x4 __attribute__((ext_vector_type(4)));

// Async global->LDS, 16B per lane. LDS dest = wave-uniform base + lane*16;
// the GLOBAL SOURCE ADDRESS IS PER-LANE. Lanes fetch their row's K-granules
// in XOR-permuted order (g8 ^ (r&7)), so the DMA lands a swizzled LDS image
// from a PLAIN row-major global plane. With BK=64 (row stride 128 B = all 32
// banks), fragment ds_read_b128s at granule (kk*4+fq)^(m&7) hit 8 bank
// groups x 2 lanes = 2-way aliasing (free). Zero VALU repack.
__device__ __forceinline__ void gload_lds16(const void* g, void* l) {
  __builtin_amdgcn_global_load_lds(
      (const __attribute__((address_space(1))) unsigned int*)g,
      (__attribute__((address_space(3))) unsigned int*)l, 16, 0, 0);
}

// ---------------------------------------------------------------------------
// Plain-fp16 MFMA GEMM: C = act(A @ B + bias), C stored as fp16 plane.
// A: MxK fp16 row-major. BT: NxK fp16 row-major (plain transpose).
// BOTH staged via source-swizzled global_load_lds. BK=64 (2 K-chunks per
// barrier interval -> half the barrier drains of BK=32).
// Epilogue: per-wave LDS bounce -> 16B coalesced C stores.
// Tile BM x 128, 256 threads. BM=128: waves 2x2; BM=64: 1x4. K%64==0.
// NOTE (r12 post-mortem): do NOT fuse extra reductions into this epilogue —
// +8 VGPR / +1KB LDS dropped occupancy 26->18% and cost 60 us per dispatch.
// ---------------------------------------------------------------------------
template <int BM>
__global__ __launch_bounds__(256) void gemm_f16_kernel(
    const _Float16* __restrict__ A, const _Float16* __restrict__ BT,
    const float* __restrict__ bias, _Float16* __restrict__ C,
    int M, int N, int K, int act) {
  constexpr int WR = (BM == 128) ? 2 : 1;  // wave grid rows
  constexpr int WC = 4 / WR;               // wave grid cols
  constexpr int MI = (BM / WR) / 16;       // m-frags per wave (4)
  constexpr int NI = (128 / WC) / 16;      // n-frags per wave (4 or 2)
  constexpr int NW = NI * 16;              // wave n-width (64 or 32)
  constexpr int CS = NW + 4;               // epilogue scratch row stride
  constexpr int GPR = NW / 8;              // 16B granules per scratch row

  __shared__ _Float16 smem[(BM + 128) * 64];
  _Float16* As = smem;             // BM x 64 (swizzled image)
  _Float16* Bs = smem + BM * 64;   // 128 x 64 (swizzled image)

  const int bn = blockIdx.x * 128, bm = blockIdx.y * BM;
  const int t = threadIdx.x;
  const int lane = t & 63, wave = t >> 6;
  const int wr = wave / WC, wc = wave % WC;
  const int m0 = wr * (BM / WR), n0 = wc * NW;
  const int fr = lane & 15, fq = lane >> 4;

  f32x4 acc[MI][NI];
#pragma unroll
  for (int i = 0; i < MI; ++i)
#pragma unroll
    for (int j = 0; j < NI; ++j) acc[i][j] = (f32x4){0.f, 0.f, 0.f, 0.f};

  for (int k0 = 0; k0 < K; k0 += 64) {
    __syncthreads();  // protect LDS from previous iteration's readers
    // ---- stage A via source-swizzled global_load_lds: BM x 64 ----
#pragma unroll
    for (int it = 0; it < BM / 32; ++it) {
      int gid = it * 256 + t;
      int r = gid >> 3;
      int q = (gid & 7) ^ (r & 7);  // fetch permuted granule
      int grow = bm + r;
      if (grow >= M) grow = M - 1;  // clamp; garbage masked in epilogue
      gload_lds16(A + (size_t)grow * K + k0 + q * 8,
                  &As[(it * 256 + wave * 64) * 8]);
    }
    // ---- stage B via source-swizzled global_load_lds: 128 x 64 ----
#pragma unroll
    for (int it = 0; it < 4; ++it) {
      int gid = it * 256 + t;
      int r = gid >> 3;
      int q = (gid & 7) ^ (r & 7);
      gload_lds16(BT + (size_t)(bn + r) * K + k0 + q * 8,
                  &Bs[(it * 256 + wave * 64) * 8]);
    }
    __syncthreads();

#pragma unroll
    for (int kk = 0; kk < 2; ++kk) {
      half8 af[MI], bf[NI];
#pragma unroll
      for (int mi = 0; mi < MI; ++mi) {
        int m = m0 + mi * 16 + fr;
        af[mi] = *(const half8*)&As[m * 64 + (((kk * 4 + fq) ^ (m & 7))) * 8];
      }
#pragma unroll
      for (int ni = 0; ni < NI; ++ni) {
        int n = n0 + ni * 16 + fr;
        bf[ni] = *(const half8*)&Bs[n * 64 + (((kk * 4 + fq) ^ (n & 7))) * 8];
      }
#pragma unroll
      for (int mi = 0; mi < MI; ++mi)
#pragma unroll
        for (int ni = 0; ni < NI; ++ni)
          acc[mi][ni] = __builtin_amdgcn_mfma_f32_16x16x32_f16(
              af[mi], bf[ni], acc[mi][ni], 0, 0, 0);
    }
  }
  // ---- epilogue: bias+act, per-wave LDS bounce, 16B coalesced stores ----
  __syncthreads();  // all K-loop LDS reads done; staging smem reusable
  _Float16* cs = smem + wave * 16 * CS;  // wave-private scratch (16 x CS)
#pragma unroll
  for (int mi = 0; mi < MI; ++mi) {
#pragma unroll
    for (int ni = 0; ni < NI; ++ni) {
      float bb = bias ? bias[bn + n0 + ni * 16 + fr] : 0.f;
#pragma unroll
      for (int j = 0; j < 4; ++j) {
        float v = acc[mi][ni][j] + bb;
        if (act == 1) v = v > 0.f ? v : expm1f(v);
        cs[(fq * 4 + j) * CS + ni * 16 + fr] = (_Float16)v;
      }
    }
    // wave-local read-back (compiler orders LDS ops via lgkmcnt)
#pragma unroll
    for (int i = 0; i < NW / 32; ++i) {
      int piece = i * 64 + lane;
      int r = piece / GPR, g = piece % GPR;
      int grow = bm + m0 + mi * 16 + r;
      if (grow < M) {
        half8 v = *(const half8*)&cs[r * CS + g * 8];
        *(half8*)&C[(size_t)grow * N + bn + n0 + g * 8] = v;
      }
    }
  }
}

// ---------------------------------------------------------------------------
// Transpose + convert weights: W (KxN fp32) -> WT (NxK fp16), PLAIN layout.
// blockIdx.z batches matrices (stride K*N).
// ---------------------------------------------------------------------------
__global__ __launch_bounds__(256) void convert_wt_kernel(
    const float* __restrict__ W, _Float16* __restrict__ WT, int K, int N) {
  __shared__ float tile[32][33];
  W += (size_t)blockIdx.z * K * N;
  WT += (size_t)blockIdx.z * K * N;
  int k0 = blockIdx.x * 32, n0 = blockIdx.y * 32;
  int t = threadIdx.x;
  int r = t >> 3, c4 = (t & 7) * 4;
  float4 v = *(const float4*)(W + (size_t)(k0 + r) * N + n0 + c4);
  tile[r][c4 + 0] = v.x;
  tile[r][c4 + 1] = v.y;
  tile[r][c4 + 2] = v.z;
  tile[r][c4 + 3] = v.w;
  __syncthreads();
  float x0 = tile[c4 + 0][r], x1 = tile[c4 + 1][r];
  float x2 = tile[c4 + 2][r], x3 = tile[c4 + 3][r];
  size_t o = (size_t)(n0 + r) * K + k0 + c4;
  *(half4*)&WT[o] = (half4){(_Float16)x0, (_Float16)x1, (_Float16)x2, (_Float16)x3};
}

// fp32 -> fp16 plane (for the external node_feat input)
__global__ void convert_f32_f16_kernel(const float* __restrict__ x,
                                       _Float16* __restrict__ y, int n4) {
  int gid = blockIdx.x * blockDim.x + threadIdx.x;
  if (gid >= n4) return;
  float4 v = *(const float4*)(x + gid * 4);
  *(half4*)(y + gid * 4) =
      (half4){(_Float16)v.x, (_Float16)v.y, (_Float16)v.z, (_Float16)v.w};
}

// ---------------------------------------------------------------------------
// CSR build (by dst): histogram -> single-block scan -> scatter.
// Scatter packs src into CSR order (csr_src).
// ---------------------------------------------------------------------------
__global__ void hist_kernel(const int* __restrict__ dst, int* __restrict__ cnt, int E) {
  int gid = blockIdx.x * blockDim.x + threadIdx.x;
  if (gid < E) atomicAdd(&cnt[dst[gid]], 1);
}

__global__ void scan_kernel(const int* __restrict__ cnt, int* __restrict__ row_ptr,
                            int* __restrict__ cursor, int n) {
  __shared__ int part[256];
  int t = threadIdx.x;
  int chunk = (n + 255) / 256;
  int s0 = t * chunk;
  int s1 = min(s0 + chunk, n);
  int sum = 0;
  for (int i = s0; i < s1; ++i) sum += cnt[i];
  part[t] = sum;
  __syncthreads();
  if (t == 0) {
    int acc = 0;
    for (int i = 0; i < 256; ++i) { int v = part[i]; part[i] = acc; acc += v; }
    row_ptr[n] = acc;
  }
  __syncthreads();
  int run = part[t];
  for (int i = s0; i < s1; ++i) {
    row_ptr[i] = run;
    cursor[i] = run;
    run += cnt[i];
  }
}

__global__ void scatter_kernel(const int* __restrict__ src, const int* __restrict__ dst,
                               int* __restrict__ cursor, int* __restrict__ csr_src,
                               int E) {
  int gid = blockIdx.x * blockDim.x + threadIdx.x;
  if (gid < E) {
    int d = dst[gid];
    int pos = atomicAdd(&cursor[d], 1);
    csr_src[pos] = src[gid];
  }
}

// ---------------------------------------------------------------------------
// GAT pieces (feat fp16 plane; edges in CSR order)
// ---------------------------------------------------------------------------
__global__ __launch_bounds__(256) void el_er_kernel(
    const _Float16* __restrict__ feat, const float* __restrict__ al,
    const float* __restrict__ ar, float* __restrict__ el, float* __restrict__ er) {
  int n = blockIdx.x;
  int t = threadIdx.x;
  int h = t >> 6, lane = t & 63;
  half8 f = *(const half8*)(feat + (size_t)n * HDTOT + h * HD + lane * 8);
  const float* ap = al + h * HD + lane * 8;
  const float* rp = ar + h * HD + lane * 8;
  float4 a0 = *(const float4*)ap, a1 = *(const float4*)(ap + 4);
  float4 r0 = *(const float4*)rp, r1 = *(const float4*)(rp + 4);
  float f0 = (float)f[0], f1 = (float)f[1], f2 = (float)f[2], f3 = (float)f[3];
  float f4 = (float)f[4], f5 = (float)f[5], f6 = (float)f[6], f7 = (float)f[7];
  float sl = f0 * a0.x + f1 * a0.y + f2 * a0.z + f3 * a0.w +
             f4 * a1.x + f5 * a1.y + f6 * a1.z + f7 * a1.w;
  float sr = f0 * r0.x + f1 * r0.y + f2 * r0.z + f3 * r0.w +
             f4 * r1.x + f5 * r1.y + f6 * r1.z + f7 * r1.w;
  for (int off = 32; off; off >>= 1) {
    sl += __shfl_down(sl, off);
    sr += __shfl_down(sr, off);
  }
  if (lane == 0) {
    el[n * NH + h] = sl;
    er[n * NH + h] = sr;
  }
}

// Fused per-(node,head) edge softmax: leaky-relu logits over the CSR range
// -> max -> exp -> sum -> write NORMALIZED weights (a = ex * (1/sum)).
// Fast path (degree <= 64): logits stay in registers, single gather pass.
__global__ __launch_bounds__(256) void edge_softmax_kernel(
    const float* __restrict__ el, const float* __restrict__ er,
    const int* __restrict__ csr_src, const int* __restrict__ row_ptr,
    float* __restrict__ e_buf) {
  int n = blockIdx.x;
  int t = threadIdx.x;
  int h = t >> 6, lane = t & 63;
  int s = row_ptr[n], epos = row_ptr[n + 1];
  int deg = epos - s;
  if (deg == 0) return;
  float ern = er[n * NH + h];
  if (deg <= 64) {
    int p = s + lane;
    bool on = lane < deg;
    float logit = 0.f;
    float m = -INFINITY;
    if (on) {
      float v = el[csr_src[p] * NH + h] + ern;
      logit = v >= 0.f ? v : 0.2f * v;
      m = logit;
    }
#pragma unroll
    for (int off = 32; off; off >>= 1) m = fmaxf(m, __shfl_xor(m, off));
    float ex = on ? expf(logit - m) : 0.f;
    float sum = ex;
#pragma unroll
    for (int off = 32; off; off >>= 1) sum += __shfl_xor(sum, off);
    float inv = 1.f / sum;
    if (on) e_buf[p * NH + h] = ex * inv;
    return;
  }
  float m = -INFINITY;
  for (int p = s + lane; p < epos; p += 64) {
    float v = el[csr_src[p] * NH + h] + ern;
    v = v >= 0.f ? v : 0.2f * v;
    e_buf[p * NH + h] = v;
    m = fmaxf(m, v);
  }
  for (int off = 32; off; off >>= 1) m = fmaxf(m, __shfl_xor(m, off));
  float sum = 0.f;
  for (int p = s + lane; p < epos; p += 64) {
    float ex = expf(e_buf[p * NH + h] - m);
    e_buf[p * NH + h] = ex;
    sum += ex;
  }
  for (int off = 32; off; off >>= 1) sum += __shfl_xor(sum, off);
  float inv = 1.f / sum;
  for (int p = s + lane; p < epos; p += 64) e_buf[p * NH + h] *= inv;
}

// out[n,:] = sum over CSR range feat[csr_src[p],:]*a[p] + bias.
// 4-deep edge unroll for memory-level parallelism (L3-latency hiding).
__global__ __launch_bounds__(256) void aggregate_kernel(
    const _Float16* __restrict__ feat, const float* __restrict__ e_buf,
    const int* __restrict__ row_ptr, const int* __restrict__ csr_src,
    const float* __restrict__ bias, _Float16* __restrict__ out) {
  int n = blockIdx.x;
  int t = threadIdx.x;
  int base = t * 8;
  int h = t >> 6;
  float acc[8] = {0.f, 0.f, 0.f, 0.f, 0.f, 0.f, 0.f, 0.f};
  int s = row_ptr[n], epos = row_ptr[n + 1];
  int p = s;
  for (; p + 4 <= epos; p += 4) {
    int sn0 = csr_src[p + 0], sn1 = csr_src[p + 1];
    int sn2 = csr_src[p + 2], sn3 = csr_src[p + 3];
    float a0 = e_buf[(p + 0) * NH + h];
    float a1 = e_buf[(p + 1) * NH + h];
    float a2 = e_buf[(p + 2) * NH + h];
    float a3 = e_buf[(p + 3) * NH + h];
    half8 f0 = *(const half8*)(feat + (size_t)sn0 * HDTOT + base);
    half8 f1 = *(const half8*)(feat + (size_t)sn1 * HDTOT + base);
    half8 f2 = *(const half8*)(feat + (size_t)sn2 * HDTOT + base);
    half8 f3 = *(const half8*)(feat + (size_t)sn3 * HDTOT + base);
#pragma unroll
    for (int i = 0; i < 8; ++i)
      acc[i] += a0 * (float)f0[i] + a1 * (float)f1[i] +
                a2 * (float)f2[i] + a3 * (float)f3[i];
  }
  for (; p < epos; ++p) {
    int sn = csr_src[p];
    float a = e_buf[p * NH + h];
    half8 f = *(const half8*)(feat + (size_t)sn * HDTOT + base);
#pragma unroll
    for (int i = 0; i < 8; ++i) acc[i] += a * (float)f[i];
  }
  float4 b0 = *(const float4*)(bias + base);
  float4 b1 = *(const float4*)(bias + base + 4);
  half8 o;
  o[0] = (_Float16)(acc[0] + b0.x); o[1] = (_Float16)(acc[1] + b0.y);
  o[2] = (_Float16)(acc[2] + b0.z); o[3] = (_Float16)(acc[3] + b0.w);
  o[4] = (_Float16)(acc[4] + b1.x); o[5] = (_Float16)(acc[5] + b1.y);
  o[6] = (_Float16)(acc[6] + b1.z); o[7] = (_Float16)(acc[7] + b1.w);
  *(half8*)(out + (size_t)n * HDTOT + base) = o;
}

// ---------------------------------------------------------------------------
// Pooling (graph_id sorted -> segmented reduction) + head
// ---------------------------------------------------------------------------
__global__ __launch_bounds__(512) void pool_kernel(
    const _Float16* __restrict__ h, const int* __restrict__ graph_id,
    float* __restrict__ hg, float* __restrict__ counts) {
  int g = blockIdx.x;
  __shared__ int s_lo, s_hi;
  if (threadIdx.x == 0) {
    int lo = 0, hi = N_NODES;
    while (lo < hi) { int m = (lo + hi) >> 1; if (graph_id[m] < g) lo = m + 1; else hi = m; }
    s_lo = lo;
    int lo2 = lo, hi2 = N_NODES;
    while (lo2 < hi2) { int m = (lo2 + hi2) >> 1; if (graph_id[m] < g + 1) lo2 = m + 1; else hi2 = m; }
    s_hi = lo2;
  }
  __syncthreads();
  int lo = s_lo, hi = s_hi;
  int col = threadIdx.x;
  float acc = 0.f;
  for (int n = lo; n < hi; ++n) acc += (float)h[(size_t)n * HFEAT + col];
  hg[g * HFEAT + col] = acc;
  if (col == 0) counts[g] = (float)(hi - lo);
}

__global__ __launch_bounds__(256) void final_kernel(
    const float* __restrict__ hg, const float* __restrict__ counts,
    const float* __restrict__ gamma, const float* __restrict__ beta,
    const float* __restrict__ Whfc, const float* __restrict__ bhfc,
    const float* __restrict__ Wf, const float* __restrict__ bf,
    float* __restrict__ out) {
  __shared__ float sh[HFEAT];
  __shared__ float st[HFEAT];
  __shared__ float r0[4], r1[4];
  int g = blockIdx.x, t = threadIdx.x;
  float invc = 1.f / fmaxf(counts[g], 1.f);
  float bnscale = rsqrtf(1.f + 1e-5f);
  for (int j = t; j < HFEAT; j += 256) {
    float v = hg[g * HFEAT + j] * invc;
    sh[j] = v * bnscale * gamma[j] + beta[j];
  }
  __syncthreads();
  for (int j = t; j < HFEAT; j += 256) {
    float acc = bhfc[j];
    for (int k = 0; k < HFEAT; ++k) acc += sh[k] * Whfc[k * HFEAT + j];
    st[j] = acc > 0.f ? acc : expm1f(acc);
  }
  __syncthreads();
  float p0 = 0.f, p1 = 0.f;
  for (int j = t; j < HFEAT; j += 256) {
    p0 += st[j] * Wf[j * 2 + 0];
    p1 += st[j] * Wf[j * 2 + 1];
  }
  for (int off = 32; off; off >>= 1) {
    p0 += __shfl_down(p0, off);
    p1 += __shfl_down(p1, off);
  }
  int w = t >> 6;
  if ((t & 63) == 0) { r0[w] = p0; r1[w] = p1; }
  __syncthreads();
  if (t == 0) {
    out[g * 2 + 0] = r0[0] + r0[1] + r0[2] + r0[3] + bf[0];
    out[g * 2 + 1] = r1[0] + r1[1] + r1[2] + r1[3] + bf[1];
  }
}

// ---------------------------------------------------------------------------
// Host-side launch
// ---------------------------------------------------------------------------
static void gemm_raw(const _Float16* A, const _Float16* wt, const float* bias,
                     _Float16* C, int M, int N, int K, int act,
                     bool small_m_tile, hipStream_t stream) {
  if (small_m_tile) {
    dim3 grid(N / 128, (M + 63) / 64);
    hipLaunchKernelGGL(gemm_f16_kernel<64>, grid, dim3(256), 0, stream,
                       A, wt, bias, C, M, N, K, act);
  } else {
    dim3 grid(N / 128, (M + 127) / 128);
    hipLaunchKernelGGL(gemm_f16_kernel<128>, grid, dim3(256), 0, stream,
                       A, wt, bias, C, M, N, K, act);
  }
}

static void gemm(const _Float16* A, const float* W, _Float16* wt,
                 const float* bias, _Float16* C, int M, int N, int K, int act,
                 bool small_m_tile, hipStream_t stream) {
  hipLaunchKernelGGL(convert_wt_kernel, dim3(K / 32, N / 32, 1), dim3(256),
                     0, stream, W, wt, K, N);
  gemm_raw(A, wt, bias, C, M, N, K, act, small_m_tile, stream);
}

static void gat_layer(const _Float16* h_in, int K_in, const float* W, _Float16* wt,
                      const float* al, const float* ar, const float* b,
                      const int* row_ptr, const int* csr_src,
                      _Float16* featbuf, float* el, float* er,
                      float* e_buf, _Float16* out, hipStream_t stream) {
  gemm(h_in, W, wt, nullptr, featbuf, N_NODES, HDTOT, K_in, 0, false, stream);
  hipLaunchKernelGGL(el_er_kernel, dim3(N_NODES), dim3(256), 0, stream, featbuf, al, ar, el, er);
  hipLaunchKernelGGL(edge_softmax_kernel, dim3(N_NODES), dim3(256), 0, stream,
                     el, er, csr_src, row_ptr, e_buf);
  hipLaunchKernelGGL(aggregate_kernel, dim3(N_NODES), dim3(256), 0, stream,
                     featbuf, e_buf, row_ptr, csr_src, b, out);
}

extern "C" void kernel_launch(void* const* d_in, const int* in_sizes, int n_in,
                              void* d_out, int out_size, void* d_ws, size_t ws_size,
                              hipStream_t stream) {
  const float* node_feat = (const float*)d_in[0];
  const float* W1 = (const float*)d_in[2];
  const float* al1 = (const float*)d_in[3];
  const float* ar1 = (const float*)d_in[4];
  const float* b1 = (const float*)d_in[5];
  const float* W2 = (const float*)d_in[6];
  const float* al2 = (const float*)d_in[7];
  const float* ar2 = (const float*)d_in[8];
  const float* b2 = (const float*)d_in[9];
  const float* Wfc = (const float*)d_in[10];
  const float* bfc = (const float*)d_in[11];
  const float* Wh = (const float*)d_in[14];
  const float* bh = (const float*)d_in[15];
  const float* gamma = (const float*)d_in[16];
  const float* beta = (const float*)d_in[17];
  const float* Whfc = (const float*)d_in[18];
  const float* bhfc = (const float*)d_in[19];
  const float* Wf = (const float*)d_in[20];
  const float* bf = (const float*)d_in[21];
  const int* src = (const int*)d_in[22];
  const int* dst = (const int*)d_in[23];
  const int* graph_id = (const int*)d_in[24];
  float* out = (float*)d_out;

  // Workspace carve-up
  _Float16* P0 = (_Float16*)d_ws;                 // 10000*2048 fp16
  _Float16* P1 = P0 + (size_t)N_NODES * HDTOT;    // 10000*2048 fp16
  _Float16* Pin = P1 + (size_t)N_NODES * HDTOT;   // 10000*768 fp16
  _Float16* wt = Pin + (size_t)N_NODES * EMB;     // 2048*2048 fp16 (shared)
  _Float16* whh = wt + (size_t)2048 * 2048;       // 8*512*512 fp16 (hidden)
  float* el = (float*)(whh + (size_t)8 * HFEAT * HFEAT);
  float* er = el + N_NODES * NH;
  float* e_buf = er + N_NODES * NH;       // N_EDGES*NH (CSR order, normalized)
  float* hg = e_buf + (size_t)N_EDGES * NH;
  float* counts = hg + N_GRAPHS * HFEAT;
  int* cnt = (int*)(counts + N_GRAPHS);
  int* row_ptr = cnt + N_NODES;           // N_NODES+1
  int* cursor = row_ptr + N_NODES + 1;
  int* csr_src = cursor + N_NODES;        // N_EDGES

  // --- CSR build (by dst), once per launch ---
  hipMemsetAsync(cnt, 0, N_NODES * sizeof(int), stream);
  hipLaunchKernelGGL(hist_kernel, dim3((N_EDGES + 255) / 256), dim3(256), 0, stream,
                     dst, cnt, N_EDGES);
  hipLaunchKernelGGL(scan_kernel, dim3(1), dim3(256), 0, stream, cnt, row_ptr, cursor, N_NODES);
  hipLaunchKernelGGL(scatter_kernel, dim3((N_EDGES + 255) / 256), dim3(256), 0, stream,
                     src, dst, cursor, csr_src, N_EDGES);

  // --- node_feat -> fp16 plane; hidden weights -> transposed fp16 (batched) ---
  int n4 = N_NODES * EMB / 4;
  hipLaunchKernelGGL(convert_f32_f16_kernel, dim3((n4 + 255) / 256), dim3(256), 0, stream,
                     node_feat, Pin, n4);
  hipLaunchKernelGGL(convert_wt_kernel, dim3(HFEAT / 32, HFEAT / 32, 8),
                     dim3(256), 0, stream, Wh, whh, HFEAT, HFEAT);

  // --- GAT layer 1: Pin(768) -> feat P0 -> h1 P1 (2048) ---
  gat_layer(Pin, EMB, W1, wt, al1, ar1, b1, row_ptr, csr_src,
            P0, el, er, e_buf, P1, stream);
  // --- GAT layer 2: P1(2048) -> feat P0 -> h2 P1 (2048) ---
  gat_layer(P1, HDTOT, W2, wt, al2, ar2, b2, row_ptr, csr_src,
            P0, el, er, e_buf, P1, stream);

  // --- h = elu(P1 @ Wfc + bfc) -> P0 (N x 512) ---
  gemm(P1, Wfc, wt, bfc, P0, N_NODES, HFEAT, HDTOT, 1, true, stream);

  // --- 8 hidden layers: chained gemm<64>, weights pre-converted ---
  _Float16* cur = P0;
  _Float16* nxt = P1;
  for (int i = 0; i < 8; ++i) {
    gemm_raw(cur, whh + (size_t)i * HFEAT * HFEAT, bh + (size_t)i * HFEAT, nxt,
             N_NODES, HFEAT, HFEAT, 1, true, stream);
    _Float16* tmp = cur; cur = nxt; nxt = tmp;
  }
  // after 8 swaps, cur == P0 holds the final h

  // --- mean pool per graph ---
  hipLaunchKernelGGL(pool_kernel, dim3(N_GRAPHS), dim3(512), 0, stream,
                     cur, graph_id, hg, counts);

  // --- BN + fc + classifier ---
  hipLaunchKernelGGL(final_kernel, dim3(N_GRAPHS), dim3(256), 0, stream,
                     hg, counts, gamma, beta, Whfc, bhfc, Wf, bf, out);
}

// Round 14
// 703.523 us; speedup vs baseline: 1.1251x; 1.0871x over previous
//
#include <hip/hip_runtime.h>
#include <hip/hip_bf16.h>
#include <math.h>

// Problem constants (from reference)
#define N_NODES 10000
#define N_EDGES 80000
#define N_GRAPHS 64
#define NH 4
#define HD 512
#define HDTOT 2048   // NH*HD
#define EMB 768
#define HFEAT 512
#define MAXDEG 512   // LDS softmax-weight capacity per node

typedef _Float16 half8 __attribute__((ext_vector_type(8)));
typedef _Float16 half4 __attribute__((ext_vector_type(4)));
typedef float f32x4 __attribute__((ext_vector_type(4)));

// Async global->LDS, 16B per lane. LDS dest = wave-uniform base + lane*16;
// the GLOBAL SOURCE ADDRESS IS PER-LANE. Lanes fetch their row's K-granules
// in XOR-permuted order (g8 ^ (r&7)), so the DMA lands a swizzled LDS image
// from a PLAIN row-major global plane. With BK=64 (row stride 128 B = all 32
// banks), fragment ds_read_b128s at granule (kk*4+fq)^(m&7) hit 8 bank
// groups x 2 lanes = 2-way aliasing (free). Zero VALU repack.
__device__ __forceinline__ void gload_lds16(const void* g, void* l) {
  __builtin_amdgcn_global_load_lds(
      (const __attribute__((address_space(1))) unsigned int*)g,
      (__attribute__((address_space(3))) unsigned int*)l, 16, 0, 0);
}

// ---------------------------------------------------------------------------
// Plain-fp16 MFMA GEMM: C = act(A @ B + bias), C stored as fp16 plane.
// A: MxK fp16 row-major. BT: NxK fp16 row-major (plain transpose).
// BOTH staged via source-swizzled global_load_lds. BK=64.
// Epilogue: per-wave LDS bounce -> 16B coalesced C stores.
// Tile BM x 128, 256 threads. BM=128: waves 2x2; BM=64: 1x4. K%64==0.
// NOTE (r12 post-mortem): do NOT fuse extra reductions into this epilogue —
// +8 VGPR / +1KB LDS dropped occupancy 26->18% and cost 60 us per dispatch.
// This kernel is at the documented m97-structure plateau (MfmaUtil ~35%).
// ---------------------------------------------------------------------------
template <int BM>
__global__ __launch_bounds__(256) void gemm_f16_kernel(
    const _Float16* __restrict__ A, const _Float16* __restrict__ BT,
    const float* __restrict__ bias, _Float16* __restrict__ C,
    int M, int N, int K, int act) {
  constexpr int WR = (BM == 128) ? 2 : 1;  // wave grid rows
  constexpr int WC = 4 / WR;               // wave grid cols
  constexpr int MI = (BM / WR) / 16;       // m-frags per wave (4)
  constexpr int NI = (128 / WC) / 16;      // n-frags per wave (4 or 2)
  constexpr int NW = NI * 16;              // wave n-width (64 or 32)
  constexpr int CS = NW + 4;               // epilogue scratch row stride
  constexpr int GPR = NW / 8;              // 16B granules per scratch row

  __shared__ _Float16 smem[(BM + 128) * 64];
  _Float16* As = smem;             // BM x 64 (swizzled image)
  _Float16* Bs = smem + BM * 64;   // 128 x 64 (swizzled image)

  const int bn = blockIdx.x * 128, bm = blockIdx.y * BM;
  const int t = threadIdx.x;
  const int lane = t & 63, wave = t >> 6;
  const int wr = wave / WC, wc = wave % WC;
  const int m0 = wr * (BM / WR), n0 = wc * NW;
  const int fr = lane & 15, fq = lane >> 4;

  f32x4 acc[MI][NI];
#pragma unroll
  for (int i = 0; i < MI; ++i)
#pragma unroll
    for (int j = 0; j < NI; ++j) acc[i][j] = (f32x4){0.f, 0.f, 0.f, 0.f};

  for (int k0 = 0; k0 < K; k0 += 64) {
    __syncthreads();  // protect LDS from previous iteration's readers
    // ---- stage A via source-swizzled global_load_lds: BM x 64 ----
#pragma unroll
    for (int it = 0; it < BM / 32; ++it) {
      int gid = it * 256 + t;
      int r = gid >> 3;
      int q = (gid & 7) ^ (r & 7);  // fetch permuted granule
      int grow = bm + r;
      if (grow >= M) grow = M - 1;  // clamp; garbage masked in epilogue
      gload_lds16(A + (size_t)grow * K + k0 + q * 8,
                  &As[(it * 256 + wave * 64) * 8]);
    }
    // ---- stage B via source-swizzled global_load_lds: 128 x 64 ----
#pragma unroll
    for (int it = 0; it < 4; ++it) {
      int gid = it * 256 + t;
      int r = gid >> 3;
      int q = (gid & 7) ^ (r & 7);
      gload_lds16(BT + (size_t)(bn + r) * K + k0 + q * 8,
                  &Bs[(it * 256 + wave * 64) * 8]);
    }
    __syncthreads();

#pragma unroll
    for (int kk = 0; kk < 2; ++kk) {
      half8 af[MI], bf[NI];
#pragma unroll
      for (int mi = 0; mi < MI; ++mi) {
        int m = m0 + mi * 16 + fr;
        af[mi] = *(const half8*)&As[m * 64 + (((kk * 4 + fq) ^ (m & 7))) * 8];
      }
#pragma unroll
      for (int ni = 0; ni < NI; ++ni) {
        int n = n0 + ni * 16 + fr;
        bf[ni] = *(const half8*)&Bs[n * 64 + (((kk * 4 + fq) ^ (n & 7))) * 8];
      }
#pragma unroll
      for (int mi = 0; mi < MI; ++mi)
#pragma unroll
        for (int ni = 0; ni < NI; ++ni)
          acc[mi][ni] = __builtin_amdgcn_mfma_f32_16x16x32_f16(
              af[mi], bf[ni], acc[mi][ni], 0, 0, 0);
    }
  }
  // ---- epilogue: bias+act, per-wave LDS bounce, 16B coalesced stores ----
  __syncthreads();  // all K-loop LDS reads done; staging smem reusable
  _Float16* cs = smem + wave * 16 * CS;  // wave-private scratch (16 x CS)
#pragma unroll
  for (int mi = 0; mi < MI; ++mi) {
#pragma unroll
    for (int ni = 0; ni < NI; ++ni) {
      float bb = bias ? bias[bn + n0 + ni * 16 + fr] : 0.f;
#pragma unroll
      for (int j = 0; j < 4; ++j) {
        float v = acc[mi][ni][j] + bb;
        if (act == 1) v = v > 0.f ? v : expm1f(v);
        cs[(fq * 4 + j) * CS + ni * 16 + fr] = (_Float16)v;
      }
    }
    // wave-local read-back (compiler orders LDS ops via lgkmcnt)
#pragma unroll
    for (int i = 0; i < NW / 32; ++i) {
      int piece = i * 64 + lane;
      int r = piece / GPR, g = piece % GPR;
      int grow = bm + m0 + mi * 16 + r;
      if (grow < M) {
        half8 v = *(const half8*)&cs[r * CS + g * 8];
        *(half8*)&C[(size_t)grow * N + bn + n0 + g * 8] = v;
      }
    }
  }
}

// ---------------------------------------------------------------------------
// Transpose + convert weights: W (KxN fp32) -> WT (NxK fp16), PLAIN layout.
// blockIdx.z batches matrices (stride K*N).
// ---------------------------------------------------------------------------
__global__ __launch_bounds__(256) void convert_wt_kernel(
    const float* __restrict__ W, _Float16* __restrict__ WT, int K, int N) {
  __shared__ float tile[32][33];
  W += (size_t)blockIdx.z * K * N;
  WT += (size_t)blockIdx.z * K * N;
  int k0 = blockIdx.x * 32, n0 = blockIdx.y * 32;
  int t = threadIdx.x;
  int r = t >> 3, c4 = (t & 7) * 4;
  float4 v = *(const float4*)(W + (size_t)(k0 + r) * N + n0 + c4);
  tile[r][c4 + 0] = v.x;
  tile[r][c4 + 1] = v.y;
  tile[r][c4 + 2] = v.z;
  tile[r][c4 + 3] = v.w;
  __syncthreads();
  float x0 = tile[c4 + 0][r], x1 = tile[c4 + 1][r];
  float x2 = tile[c4 + 2][r], x3 = tile[c4 + 3][r];
  size_t o = (size_t)(n0 + r) * K + k0 + c4;
  *(half4*)&WT[o] = (half4){(_Float16)x0, (_Float16)x1, (_Float16)x2, (_Float16)x3};
}

// fp32 -> fp16 plane (for the external node_feat input)
__global__ void convert_f32_f16_kernel(const float* __restrict__ x,
                                       _Float16* __restrict__ y, int n4) {
  int gid = blockIdx.x * blockDim.x + threadIdx.x;
  if (gid >= n4) return;
  float4 v = *(const float4*)(x + gid * 4);
  *(half4*)(y + gid * 4) =
      (half4){(_Float16)v.x, (_Float16)v.y, (_Float16)v.z, (_Float16)v.w};
}

// ---------------------------------------------------------------------------
// CSR build (by dst): histogram -> single-block scan -> scatter.
// Scatter packs src into CSR order (csr_src).
// ---------------------------------------------------------------------------
__global__ void hist_kernel(const int* __restrict__ dst, int* __restrict__ cnt, int E) {
  int gid = blockIdx.x * blockDim.x + threadIdx.x;
  if (gid < E) atomicAdd(&cnt[dst[gid]], 1);
}

__global__ void scan_kernel(const int* __restrict__ cnt, int* __restrict__ row_ptr,
                            int* __restrict__ cursor, int n) {
  __shared__ int part[256];
  int t = threadIdx.x;
  int chunk = (n + 255) / 256;
  int s0 = t * chunk;
  int s1 = min(s0 + chunk, n);
  int sum = 0;
  for (int i = s0; i < s1; ++i) sum += cnt[i];
  part[t] = sum;
  __syncthreads();
  if (t == 0) {
    int acc = 0;
    for (int i = 0; i < 256; ++i) { int v = part[i]; part[i] = acc; acc += v; }
    row_ptr[n] = acc;
  }
  __syncthreads();
  int run = part[t];
  for (int i = s0; i < s1; ++i) {
    row_ptr[i] = run;
    cursor[i] = run;
    run += cnt[i];
  }
}

__global__ void scatter_kernel(const int* __restrict__ src, const int* __restrict__ dst,
                               int* __restrict__ cursor, int* __restrict__ csr_src,
                               int E) {
  int gid = blockIdx.x * blockDim.x + threadIdx.x;
  if (gid < E) {
    int d = dst[gid];
    int pos = atomicAdd(&cursor[d], 1);
    csr_src[pos] = src[gid];
  }
}

// ---------------------------------------------------------------------------
// GAT pieces (feat fp16 plane; edges in CSR order)
// ---------------------------------------------------------------------------
__global__ __launch_bounds__(256) void el_er_kernel(
    const _Float16* __restrict__ feat, const float* __restrict__ al,
    const float* __restrict__ ar, float* __restrict__ el, float* __restrict__ er) {
  int n = blockIdx.x;
  int t = threadIdx.x;
  int h = t >> 6, lane = t & 63;
  half8 f = *(const half8*)(feat + (size_t)n * HDTOT + h * HD + lane * 8);
  const float* ap = al + h * HD + lane * 8;
  const float* rp = ar + h * HD + lane * 8;
  float4 a0 = *(const float4*)ap, a1 = *(const float4*)(ap + 4);
  float4 r0 = *(const float4*)rp, r1 = *(const float4*)(rp + 4);
  float f0 = (float)f[0], f1 = (float)f[1], f2 = (float)f[2], f3 = (float)f[3];
  float f4 = (float)f[4], f5 = (float)f[5], f6 = (float)f[6], f7 = (float)f[7];
  float sl = f0 * a0.x + f1 * a0.y + f2 * a0.z + f3 * a0.w +
             f4 * a1.x + f5 * a1.y + f6 * a1.z + f7 * a1.w;
  float sr = f0 * r0.x + f1 * r0.y + f2 * r0.z + f3 * r0.w +
             f4 * r1.x + f5 * r1.y + f6 * r1.z + f7 * r1.w;
  for (int off = 32; off; off >>= 1) {
    sl += __shfl_down(sl, off);
    sr += __shfl_down(sr, off);
  }
  if (lane == 0) {
    el[n * NH + h] = sl;
    er[n * NH + h] = sr;
  }
}

// ---------------------------------------------------------------------------
// FUSED per-node edge-softmax + aggregate.
// Phase 1 (threads as 4 heads x 64 lanes): leaky-relu logits over the CSR
// range -> max -> exp -> sum -> normalized weights into LDS wl[h][q]
// (register path for deg<=64; global e_buf fallback for deg>MAXDEG).
// Phase 2 (threads as 256 x 8-col granules): out[n,:] = sum_p a[p]*feat[src]
// + bias, weights read from LDS (64-lane broadcast, free).
// Arithmetic identical to the previous two-kernel path (a = ex * (1/sum)).
// ---------------------------------------------------------------------------
__global__ __launch_bounds__(256) void softmax_aggregate_kernel(
    const _Float16* __restrict__ feat, const float* __restrict__ el,
    const float* __restrict__ er, const int* __restrict__ row_ptr,
    const int* __restrict__ csr_src, float* __restrict__ e_buf,
    const float* __restrict__ bias, _Float16* __restrict__ out) {
  __shared__ float wl[NH][MAXDEG];
  int n = blockIdx.x;
  int t = threadIdx.x;
  int h = t >> 6, lane = t & 63;
  int s = row_ptr[n], epos = row_ptr[n + 1];
  int deg = epos - s;
  bool lds_w = (deg <= MAXDEG);

  // ---- phase 1: softmax weights ----
  if (deg > 0) {
    float ern = er[n * NH + h];
    if (deg <= 64) {
      int p = s + lane;
      bool on = lane < deg;
      float logit = 0.f;
      float m = -INFINITY;
      if (on) {
        float v = el[csr_src[p] * NH + h] + ern;
        logit = v >= 0.f ? v : 0.2f * v;
        m = logit;
      }
#pragma unroll
      for (int off = 32; off; off >>= 1) m = fmaxf(m, __shfl_xor(m, off));
      float ex = on ? expf(logit - m) : 0.f;
      float sum = ex;
#pragma unroll
      for (int off = 32; off; off >>= 1) sum += __shfl_xor(sum, off);
      float inv = 1.f / sum;
      if (on) wl[h][lane] = ex * inv;
    } else if (lds_w) {
      float m = -INFINITY;
      for (int p = s + lane; p < epos; p += 64) {
        float v = el[csr_src[p] * NH + h] + ern;
        v = v >= 0.f ? v : 0.2f * v;
        wl[h][p - s] = v;
        m = fmaxf(m, v);
      }
      for (int off = 32; off; off >>= 1) m = fmaxf(m, __shfl_xor(m, off));
      float sum = 0.f;
      for (int p = s + lane; p < epos; p += 64) {
        float ex = expf(wl[h][p - s] - m);
        wl[h][p - s] = ex;
        sum += ex;
      }
      for (int off = 32; off; off >>= 1) sum += __shfl_xor(sum, off);
      float inv = 1.f / sum;
      for (int p = s + lane; p < epos; p += 64) wl[h][p - s] *= inv;
    } else {
      // rare fallback: weights via global scratch
      float m = -INFINITY;
      for (int p = s + lane; p < epos; p += 64) {
        float v = el[csr_src[p] * NH + h] + ern;
        v = v >= 0.f ? v : 0.2f * v;
        e_buf[p * NH + h] = v;
        m = fmaxf(m, v);
      }
      for (int off = 32; off; off >>= 1) m = fmaxf(m, __shfl_xor(m, off));
      float sum = 0.f;
      for (int p = s + lane; p < epos; p += 64) {
        float ex = expf(e_buf[p * NH + h] - m);
        e_buf[p * NH + h] = ex;
        sum += ex;
      }
      for (int off = 32; off; off >>= 1) sum += __shfl_xor(sum, off);
      float inv = 1.f / sum;
      for (int p = s + lane; p < epos; p += 64) e_buf[p * NH + h] *= inv;
    }
  }
  __syncthreads();

  // ---- phase 2: weighted aggregation (4-deep unroll for MLP) ----
  int base = t * 8;
  float acc[8] = {0.f, 0.f, 0.f, 0.f, 0.f, 0.f, 0.f, 0.f};
  int p = s;
  for (; p + 4 <= epos; p += 4) {
    int q = p - s;
    int sn0 = csr_src[p + 0], sn1 = csr_src[p + 1];
    int sn2 = csr_src[p + 2], sn3 = csr_src[p + 3];
    float a0 = lds_w ? wl[h][q + 0] : e_buf[(p + 0) * NH + h];
    float a1 = lds_w ? wl[h][q + 1] : e_buf[(p + 1) * NH + h];
    float a2 = lds_w ? wl[h][q + 2] : e_buf[(p + 2) * NH + h];
    float a3 = lds_w ? wl[h][q + 3] : e_buf[(p + 3) * NH + h];
    half8 f0 = *(const half8*)(feat + (size_t)sn0 * HDTOT + base);
    half8 f1 = *(const half8*)(feat + (size_t)sn1 * HDTOT + base);
    half8 f2 = *(const half8*)(feat + (size_t)sn2 * HDTOT + base);
    half8 f3 = *(const half8*)(feat + (size_t)sn3 * HDTOT + base);
#pragma unroll
    for (int i = 0; i < 8; ++i)
      acc[i] += a0 * (float)f0[i] + a1 * (float)f1[i] +
                a2 * (float)f2[i] + a3 * (float)f3[i];
  }
  for (; p < epos; ++p) {
    int sn = csr_src[p];
    float a = lds_w ? wl[h][p - s] : e_buf[p * NH + h];
    half8 f = *(const half8*)(feat + (size_t)sn * HDTOT + base);
#pragma unroll
    for (int i = 0; i < 8; ++i) acc[i] += a * (float)f[i];
  }
  float4 b0 = *(const float4*)(bias + base);
  float4 b1 = *(const float4*)(bias + base + 4);
  half8 o;
  o[0] = (_Float16)(acc[0] + b0.x); o[1] = (_Float16)(acc[1] + b0.y);
  o[2] = (_Float16)(acc[2] + b0.z); o[3] = (_Float16)(acc[3] + b0.w);
  o[4] = (_Float16)(acc[4] + b1.x); o[5] = (_Float16)(acc[5] + b1.y);
  o[6] = (_Float16)(acc[6] + b1.z); o[7] = (_Float16)(acc[7] + b1.w);
  *(half8*)(out + (size_t)n * HDTOT + base) = o;
}

// ---------------------------------------------------------------------------
// FUSED pool + BN + Whfc matvec + classifier. One block per graph.
// graph_id sorted -> segmented mean; identical math to the prior two kernels.
// ---------------------------------------------------------------------------
__global__ __launch_bounds__(512) void pool_final_kernel(
    const _Float16* __restrict__ hfeat, const int* __restrict__ graph_id,
    const float* __restrict__ gamma, const float* __restrict__ beta,
    const float* __restrict__ Whfc, const float* __restrict__ bhfc,
    const float* __restrict__ Wf, const float* __restrict__ bf,
    float* __restrict__ out) {
  __shared__ float sh[HFEAT];
  __shared__ float st[HFEAT];
  __shared__ float r0[8], r1[8];
  __shared__ int s_lo, s_hi;
  int g = blockIdx.x, t = threadIdx.x;
  if (t == 0) {
    int lo = 0, hi = N_NODES;
    while (lo < hi) { int m = (lo + hi) >> 1; if (graph_id[m] < g) lo = m + 1; else hi = m; }
    s_lo = lo;
    int lo2 = lo, hi2 = N_NODES;
    while (lo2 < hi2) { int m = (lo2 + hi2) >> 1; if (graph_id[m] < g + 1) lo2 = m + 1; else hi2 = m; }
    s_hi = lo2;
  }
  __syncthreads();
  int lo = s_lo, hi = s_hi;
  int col = t;  // 512 threads = HFEAT cols
  float acc = 0.f;
  for (int n = lo; n < hi; ++n) acc += (float)hfeat[(size_t)n * HFEAT + col];
  float invc = 1.f / fmaxf((float)(hi - lo), 1.f);
  float bnscale = rsqrtf(1.f + 1e-5f);
  sh[col] = acc * invc * bnscale * gamma[col] + beta[col];
  __syncthreads();
  float a2 = bhfc[col];
  for (int k = 0; k < HFEAT; ++k) a2 += sh[k] * Whfc[k * HFEAT + col];
  st[col] = a2 > 0.f ? a2 : expm1f(a2);
  __syncthreads();
  float p0 = st[col] * Wf[col * 2 + 0];
  float p1 = st[col] * Wf[col * 2 + 1];
  for (int off = 32; off; off >>= 1) {
    p0 += __shfl_down(p0, off);
    p1 += __shfl_down(p1, off);
  }
  int w = t >> 6;
  if ((t & 63) == 0) { r0[w] = p0; r1[w] = p1; }
  __syncthreads();
  if (t == 0) {
    float q0 = bf[0], q1 = bf[1];
#pragma unroll
    for (int i = 0; i < 8; ++i) { q0 += r0[i]; q1 += r1[i]; }
    out[g * 2 + 0] = q0;
    out[g * 2 + 1] = q1;
  }
}

// ---------------------------------------------------------------------------
// Host-side launch
// ---------------------------------------------------------------------------
static void gemm_raw(const _Float16* A, const _Float16* wt, const float* bias,
                     _Float16* C, int M, int N, int K, int act,
                     bool small_m_tile, hipStream_t stream) {
  if (small_m_tile) {
    dim3 grid(N / 128, (M + 63) / 64);
    hipLaunchKernelGGL(gemm_f16_kernel<64>, grid, dim3(256), 0, stream,
                       A, wt, bias, C, M, N, K, act);
  } else {
    dim3 grid(N / 128, (M + 127) / 128);
    hipLaunchKernelGGL(gemm_f16_kernel<128>, grid, dim3(256), 0, stream,
                       A, wt, bias, C, M, N, K, act);
  }
}

static void gemm(const _Float16* A, const float* W, _Float16* wt,
                 const float* bias, _Float16* C, int M, int N, int K, int act,
                 bool small_m_tile, hipStream_t stream) {
  hipLaunchKernelGGL(convert_wt_kernel, dim3(K / 32, N / 32, 1), dim3(256),
                     0, stream, W, wt, K, N);
  gemm_raw(A, wt, bias, C, M, N, K, act, small_m_tile, stream);
}

static void gat_layer(const _Float16* h_in, int K_in, const float* W, _Float16* wt,
                      const float* al, const float* ar, const float* b,
                      const int* row_ptr, const int* csr_src,
                      _Float16* featbuf, float* el, float* er,
                      float* e_buf, _Float16* out, hipStream_t stream) {
  gemm(h_in, W, wt, nullptr, featbuf, N_NODES, HDTOT, K_in, 0, false, stream);
  hipLaunchKernelGGL(el_er_kernel, dim3(N_NODES), dim3(256), 0, stream, featbuf, al, ar, el, er);
  hipLaunchKernelGGL(softmax_aggregate_kernel, dim3(N_NODES), dim3(256), 0, stream,
                     featbuf, el, er, row_ptr, csr_src, e_buf, b, out);
}

extern "C" void kernel_launch(void* const* d_in, const int* in_sizes, int n_in,
                              void* d_out, int out_size, void* d_ws, size_t ws_size,
                              hipStream_t stream) {
  const float* node_feat = (const float*)d_in[0];
  const float* W1 = (const float*)d_in[2];
  const float* al1 = (const float*)d_in[3];
  const float* ar1 = (const float*)d_in[4];
  const float* b1 = (const float*)d_in[5];
  const float* W2 = (const float*)d_in[6];
  const float* al2 = (const float*)d_in[7];
  const float* ar2 = (const float*)d_in[8];
  const float* b2 = (const float*)d_in[9];
  const float* Wfc = (const float*)d_in[10];
  const float* bfc = (const float*)d_in[11];
  const float* Wh = (const float*)d_in[14];
  const float* bh = (const float*)d_in[15];
  const float* gamma = (const float*)d_in[16];
  const float* beta = (const float*)d_in[17];
  const float* Whfc = (const float*)d_in[18];
  const float* bhfc = (const float*)d_in[19];
  const float* Wf = (const float*)d_in[20];
  const float* bf = (const float*)d_in[21];
  const int* src = (const int*)d_in[22];
  const int* dst = (const int*)d_in[23];
  const int* graph_id = (const int*)d_in[24];
  float* out = (float*)d_out;

  // Workspace carve-up
  _Float16* P0 = (_Float16*)d_ws;                 // 10000*2048 fp16
  _Float16* P1 = P0 + (size_t)N_NODES * HDTOT;    // 10000*2048 fp16
  _Float16* Pin = P1 + (size_t)N_NODES * HDTOT;   // 10000*768 fp16
  _Float16* wt = Pin + (size_t)N_NODES * EMB;     // 2048*2048 fp16 (shared)
  _Float16* whh = wt + (size_t)2048 * 2048;       // 8*512*512 fp16 (hidden)
  float* el = (float*)(whh + (size_t)8 * HFEAT * HFEAT);
  float* er = el + N_NODES * NH;
  float* e_buf = er + N_NODES * NH;       // N_EDGES*NH (fallback scratch)
  int* cnt = (int*)(e_buf + (size_t)N_EDGES * NH);
  int* row_ptr = cnt + N_NODES;           // N_NODES+1
  int* cursor = row_ptr + N_NODES + 1;
  int* csr_src = cursor + N_NODES;        // N_EDGES

  // --- CSR build (by dst), once per launch ---
  hipMemsetAsync(cnt, 0, N_NODES * sizeof(int), stream);
  hipLaunchKernelGGL(hist_kernel, dim3((N_EDGES + 255) / 256), dim3(256), 0, stream,
                     dst, cnt, N_EDGES);
  hipLaunchKernelGGL(scan_kernel, dim3(1), dim3(256), 0, stream, cnt, row_ptr, cursor, N_NODES);
  hipLaunchKernelGGL(scatter_kernel, dim3((N_EDGES + 255) / 256), dim3(256), 0, stream,
                     src, dst, cursor, csr_src, N_EDGES);

  // --- node_feat -> fp16 plane; hidden weights -> transposed fp16 (batched) ---
  int n4 = N_NODES * EMB / 4;
  hipLaunchKernelGGL(convert_f32_f16_kernel, dim3((n4 + 255) / 256), dim3(256), 0, stream,
                     node_feat, Pin, n4);
  hipLaunchKernelGGL(convert_wt_kernel, dim3(HFEAT / 32, HFEAT / 32, 8),
                     dim3(256), 0, stream, Wh, whh, HFEAT, HFEAT);

  // --- GAT layer 1: Pin(768) -> feat P0 -> h1 P1 (2048) ---
  gat_layer(Pin, EMB, W1, wt, al1, ar1, b1, row_ptr, csr_src,
            P0, el, er, e_buf, P1, stream);
  // --- GAT layer 2: P1(2048) -> feat P0 -> h2 P1 (2048) ---
  gat_layer(P1, HDTOT, W2, wt, al2, ar2, b2, row_ptr, csr_src,
            P0, el, er, e_buf, P1, stream);

  // --- h = elu(P1 @ Wfc + bfc) -> P0 (N x 512) ---
  gemm(P1, Wfc, wt, bfc, P0, N_NODES, HFEAT, HDTOT, 1, true, stream);

  // --- 8 hidden layers: chained gemm<64>, weights pre-converted ---
  _Float16* cur = P0;
  _Float16* nxt = P1;
  for (int i = 0; i < 8; ++i) {
    gemm_raw(cur, whh + (size_t)i * HFEAT * HFEAT, bh + (size_t)i * HFEAT, nxt,
             N_NODES, HFEAT, HFEAT, 1, true, stream);
    _Float16* tmp = cur; cur = nxt; nxt = tmp;
  }
  // after 8 swaps, cur == P0 holds the final h

  // --- fused mean-pool + BN + fc + classifier ---
  hipLaunchKernelGGL(pool_final_kernel, dim3(N_GRAPHS), dim3(512), 0, stream,
                     cur, graph_id, gamma, beta, Whfc, bhfc, Wf, bf, out);
}